// Round 1
// 157.370 us; speedup vs baseline: 1.1657x; 1.1657x over previous
//
#include <hip/hip_runtime.h>
#include <math.h>

// Problem dims (fixed by reference)
#define BATCH 2048
#define GIN 128
#define GH 128
#define NE 8
#define XIN 512
#define UU 512

typedef __attribute__((ext_vector_type(8))) short short8;   // 8 bf16 in 4 VGPRs
typedef __attribute__((ext_vector_type(4))) float f32x4;

__device__ inline unsigned short f2bf(float f) {
    unsigned u = __float_as_uint(f);
    u += 0x7fffu + ((u >> 16) & 1u);
    return (unsigned short)(u >> 16);
}

__device__ inline float elu1(float x) { return x > 0.f ? x : (expf(x) - 1.f); }

// ---------------------------------------------------------------------------
// Gating MLP: fp32 exact, latency-optimized.
// 512 blocks x 256 threads; block = 4 batch rows; K=128 split across 2 halves.
// ---------------------------------------------------------------------------
__global__ __launch_bounds__(256) void gating_kernel(
    const float* __restrict__ gin, const float* __restrict__ W0, const float* __restrict__ b0,
    const float* __restrict__ W1, const float* __restrict__ b1,
    const float* __restrict__ Wo, const float* __restrict__ bo,
    float* __restrict__ g)
{
    __shared__ float xs[4][128];
    __shared__ float hs[4][128];
    __shared__ float ps[2][4][128];
    __shared__ float lp[8][4][8];
    __shared__ float ls[4][8];

    const int t = threadIdx.x;
    const int c = t & 127;          // output feature
    const int h = t >> 7;           // k-half
    const int row0 = blockIdx.x * 4;

    ((float*)xs)[t]       = gin[row0 * GIN + t];
    ((float*)xs)[t + 256] = gin[row0 * GIN + t + 256];
    __syncthreads();

    {   // layer 0
        float acc0 = 0.f, acc1 = 0.f, acc2 = 0.f, acc3 = 0.f;
        const float* Wc = W0 + c;
        #pragma unroll 8
        for (int i = h * 64; i < h * 64 + 64; ++i) {
            float w = Wc[i * GH];
            acc0 += xs[0][i] * w; acc1 += xs[1][i] * w;
            acc2 += xs[2][i] * w; acc3 += xs[3][i] * w;
        }
        ps[h][0][c] = acc0; ps[h][1][c] = acc1; ps[h][2][c] = acc2; ps[h][3][c] = acc3;
    }
    __syncthreads();
    {
        int o = t, r = o >> 7, cc = o & 127;
        hs[r][cc] = elu1(ps[0][r][cc] + ps[1][r][cc] + b0[cc]);
        o = t + 256; r = o >> 7; cc = o & 127;
        hs[r][cc] = elu1(ps[0][r][cc] + ps[1][r][cc] + b0[cc]);
    }
    __syncthreads();

    {   // layer 1
        float acc0 = 0.f, acc1 = 0.f, acc2 = 0.f, acc3 = 0.f;
        const float* Wc = W1 + c;
        #pragma unroll 8
        for (int i = h * 64; i < h * 64 + 64; ++i) {
            float w = Wc[i * GH];
            acc0 += hs[0][i] * w; acc1 += hs[1][i] * w;
            acc2 += hs[2][i] * w; acc3 += hs[3][i] * w;
        }
        ps[h][0][c] = acc0; ps[h][1][c] = acc1; ps[h][2][c] = acc2; ps[h][3][c] = acc3;
    }
    __syncthreads();
    {
        int o = t, r = o >> 7, cc = o & 127;
        xs[r][cc] = elu1(ps[0][r][cc] + ps[1][r][cc] + b1[cc]);
        o = t + 256; r = o >> 7; cc = o & 127;
        xs[r][cc] = elu1(ps[0][r][cc] + ps[1][r][cc] + b1[cc]);
    }
    __syncthreads();

    {   // output layer, 8-way k-split
        const int e = t & 7, r = (t >> 3) & 3, q = t >> 5;
        float s = 0.f;
        #pragma unroll
        for (int i = q * 16; i < q * 16 + 16; ++i) s += xs[r][i] * Wo[i * NE + e];
        lp[q][r][e] = s;
    }
    __syncthreads();
    if (t < 32) {
        const int r = t >> 3, e = t & 7;
        float s = bo[e];
        #pragma unroll
        for (int q = 0; q < 8; ++q) s += lp[q][r][e];
        ls[r][e] = s;
    }
    __syncthreads();
    if (t < 4) {
        float mx = ls[t][0];
        #pragma unroll
        for (int e = 1; e < 8; ++e) mx = fmaxf(mx, ls[t][e]);
        float s = 0.f, ex[8];
        #pragma unroll
        for (int e = 0; e < 8; ++e) { ex[e] = expf(ls[t][e] - mx); s += ex[e]; }
        float inv = 1.f / s;
        #pragma unroll
        for (int e = 0; e < 8; ++e) g[(row0 + t) * NE + e] = ex[e] * inv;
    }
}

// ---------------------------------------------------------------------------
// Convert alpha pools AND expert input fp32 -> bf16 in one kernel.
// Destination is contiguous: [ab (3*2^21)] [Xb0 (2^20)]. 4 elems/thread.
// ---------------------------------------------------------------------------
__global__ __launch_bounds__(256) void convert_kernel(
    const float* __restrict__ a0, const float* __restrict__ a1, const float* __restrict__ a2,
    const float* __restrict__ xv, unsigned short* __restrict__ dst)
{
    const long long vi = (long long)(blockIdx.x * blockDim.x + threadIdx.x) * 4;
    const int sel = (int)(vi >> 21);             // 0,1,2 = alpha pools; 3 = X (2^20 elems)
    const float* src = (sel == 0) ? a0 : (sel == 1) ? a1 : (sel == 2) ? a2 : xv;
    float4 v = *(const float4*)(src + (vi & ((1 << 21) - 1)));
    union { unsigned short us[4]; uint2 u2; } p;
    p.us[0] = f2bf(v.x); p.us[1] = f2bf(v.y); p.us[2] = f2bf(v.z); p.us[3] = f2bf(v.w);
    *(uint2*)(dst + vi) = p.u2;
}

// ---------------------------------------------------------------------------
// Fully-fused MoE layer: block tile 64(M) x 32(N), ALL 8 experts, BK=64, K=512.
// A: Xb (2048x512 bf16). Bw: alpha bf16 [e][n][i].
// Epilogue: out[b,n] = sum_e g[b,e]*(P_e[b,n] + beta[e,n]); then ELU+bf16 cast
// (layers 0,1 -> Xnext) or raw fp32 store (last layer -> out).
// No intermediate slabs, no reduce kernel.
// Grid (512/32=16, 2048/64=32) = 512 blocks -> 2 blocks/CU (drain overlap).
// ---------------------------------------------------------------------------
__global__ __launch_bounds__(256) void moe_fused_kernel(
    const unsigned short* __restrict__ A,
    const unsigned short* __restrict__ Bw,
    const float* __restrict__ g,
    const float* __restrict__ beta,
    unsigned short* __restrict__ Xnext,
    float* __restrict__ out, int last)
{
    constexpr int K = XIN;
    __shared__ unsigned short As[64 * 64];        // 8 KB
    __shared__ unsigned short Bs[8 * 32 * 64];    // 32 KB
    __shared__ float gs[64][8];                   // 2 KB
    __shared__ float bt[8][32];                   // 1 KB

    const int t = threadIdx.x;
    const int n0 = blockIdx.x * 32;
    const int m0 = blockIdx.y * 64;
    const int wave = t >> 6, lane = t & 63;
    const int wm = (wave >> 1) * 32;              // 0 or 32
    const int wn = (wave & 1) * 16;               // 0 or 16

    // stage g rows (64 x 8 contiguous) and beta tile (8 x 32); first loop
    // barrier covers visibility; only read in epilogue.
    ((float2*)gs)[t] = ((const float2*)(g + (size_t)m0 * NE))[t];
    bt[t >> 5][t & 31] = beta[(t >> 5) * UU + n0 + (t & 31)];

    f32x4 acc[8][2] = {};

    const int trow = t >> 3;        // 0..31
    const int tcol = (t & 7) * 8;   // element col within BK

    const unsigned short* Ae = A + (size_t)m0 * K;

    for (int ki = 0; ki < K; ki += 64) {
        __syncthreads();
        #pragma unroll
        for (int it = 0; it < 2; ++it) {
            const unsigned short* ga = Ae + (size_t)(trow + it * 32) * K + ki + tcol;
            __builtin_amdgcn_global_load_lds(
                (const __attribute__((address_space(1))) void*)ga,
                (__attribute__((address_space(3))) void*)(As + it * 2048 + t * 8), 16, 0, 0);
        }
        #pragma unroll
        for (int it = 0; it < 8; ++it) {
            const int rowflat = trow + it * 32;   // 0..255: e = >>5, n = &31
            const unsigned short* gb = Bw +
                ((size_t)(rowflat >> 5) * UU + n0 + (rowflat & 31)) * K + ki + tcol;
            __builtin_amdgcn_global_load_lds(
                (const __attribute__((address_space(1))) void*)gb,
                (__attribute__((address_space(3))) void*)(Bs + it * 2048 + t * 8), 16, 0, 0);
        }
        __syncthreads();

        #pragma unroll
        for (int kk = 0; kk < 64; kk += 32) {
            short8 af[2], bf[8];
            const int fr = lane & 15;
            const int fk = kk + (lane >> 4) * 8;
            af[0] = *(const short8*)(As + (wm + fr) * 64 + fk);
            af[1] = *(const short8*)(As + (wm + fr + 16) * 64 + fk);
            #pragma unroll
            for (int e = 0; e < 8; ++e)
                bf[e] = *(const short8*)(Bs + (e * 32 + wn + fr) * 64 + fk);
            #pragma unroll
            for (int e = 0; e < 8; ++e) {
                acc[e][0] = __builtin_amdgcn_mfma_f32_16x16x32_bf16(af[0], bf[e], acc[e][0], 0, 0, 0);
                acc[e][1] = __builtin_amdgcn_mfma_f32_16x16x32_bf16(af[1], bf[e], acc[e][1], 0, 0, 0);
            }
        }
    }

    // epilogue: C/D mapping col=lane&15, row=(lane>>4)*4+reg  [m89-verified]
    const int cl = lane & 15, rq = lane >> 4;
    const int col = n0 + wn + cl;
    #pragma unroll
    for (int i = 0; i < 2; ++i)
        #pragma unroll
        for (int r = 0; r < 4; ++r) {
            const int rl = wm + i * 16 + rq * 4 + r;
            float v = 0.f;
            #pragma unroll
            for (int e = 0; e < 8; ++e)
                v += gs[rl][e] * (acc[e][i][r] + bt[e][wn + cl]);
            if (last) out[(size_t)(m0 + rl) * UU + col] = v;
            else      Xnext[(size_t)(m0 + rl) * UU + col] = f2bf(elu1(v));
        }
}

// ---------------------------------------------------------------------------
extern "C" void kernel_launch(void* const* d_in, const int* in_sizes, int n_in,
                              void* d_out, int out_size, void* d_ws, size_t ws_size,
                              hipStream_t stream)
{
    (void)in_sizes; (void)n_in; (void)out_size; (void)ws_size;
    const float* gin = (const float*)d_in[0];
    const float* xin = (const float*)d_in[1];
    const float* W0  = (const float*)d_in[2];
    const float* b0  = (const float*)d_in[3];
    const float* W1  = (const float*)d_in[4];
    const float* b1  = (const float*)d_in[5];
    const float* Wo  = (const float*)d_in[6];
    const float* bo  = (const float*)d_in[7];
    const float* alpha[3] = {(const float*)d_in[8],  (const float*)d_in[10], (const float*)d_in[12]};
    const float* beta[3]  = {(const float*)d_in[9],  (const float*)d_in[11], (const float*)d_in[13]};
    float* out = (float*)d_out;

    // ws layout (~16.8 MB total)
    char* ws = (char*)d_ws;
    float* g = (float*)ws;                                   // 2048*8*4      = 64 KB
    size_t off = 65536;
    unsigned short* ab = (unsigned short*)(ws + off);        // 3 * 2^21 * 2  = 12.58 MB
    off += (size_t)3 * (1 << 21) * 2;
    unsigned short* Xb0 = (unsigned short*)(ws + off);       // 2048*512*2    = 2.1 MB (contiguous after ab!)
    off += (size_t)BATCH * XIN * 2;
    unsigned short* Xb1 = (unsigned short*)(ws + off);       // 2048*512*2    = 2.1 MB
    off += (size_t)BATCH * XIN * 2;

    gating_kernel<<<BATCH / 4, 256, 0, stream>>>(gin, W0, b0, W1, b1, Wo, bo, g);
    // converts 3 alpha pools + X in one pass; X lands at ab + 3*2^21 == Xb0
    convert_kernel<<<(3 * (1 << 21) + BATCH * XIN) / 4 / 256, 256, 0, stream>>>(
        alpha[0], alpha[1], alpha[2], xin, ab);

    // ping-pong X buffers: layer reads Xsrc while writing Xdst (other blocks
    // still read Xsrc rows -> must not write in place).
    unsigned short* Xsrc = Xb0;
    unsigned short* Xdst = Xb1;
    for (int l = 0; l < 3; ++l) {
        moe_fused_kernel<<<dim3(UU / 32, BATCH / 64), 256, 0, stream>>>(
            Xsrc, ab + (size_t)l * (1 << 21), g, beta[l], Xdst, out, l == 2 ? 1 : 0);
        unsigned short* tmp = Xsrc; Xsrc = Xdst; Xdst = tmp;
    }
}

// Round 2
// 153.236 us; speedup vs baseline: 1.1971x; 1.0270x over previous
//
#include <hip/hip_runtime.h>
#include <math.h>

// Problem dims (fixed by reference)
#define BATCH 2048
#define GIN 128
#define GH 128
#define NE 8
#define XIN 512
#define UU 512

typedef __attribute__((ext_vector_type(8))) short short8;   // 8 bf16 in 4 VGPRs
typedef __attribute__((ext_vector_type(4))) float f32x4;

#define AS1 __attribute__((address_space(1)))
#define AS3 __attribute__((address_space(3)))

__device__ inline unsigned short f2bf(float f) {
    unsigned u = __float_as_uint(f);
    u += 0x7fffu + ((u >> 16) & 1u);
    return (unsigned short)(u >> 16);
}

__device__ inline float elu1(float x) { return x > 0.f ? x : (expf(x) - 1.f); }

// ---------------------------------------------------------------------------
// Gating MLP: fp32 exact, latency-optimized.
// 512 blocks x 256 threads; block = 4 batch rows; K=128 split across 2 halves.
// ---------------------------------------------------------------------------
__global__ __launch_bounds__(256) void gating_kernel(
    const float* __restrict__ gin, const float* __restrict__ W0, const float* __restrict__ b0,
    const float* __restrict__ W1, const float* __restrict__ b1,
    const float* __restrict__ Wo, const float* __restrict__ bo,
    float* __restrict__ g)
{
    __shared__ float xs[4][128];
    __shared__ float hs[4][128];
    __shared__ float ps[2][4][128];
    __shared__ float lp[8][4][8];
    __shared__ float ls[4][8];

    const int t = threadIdx.x;
    const int c = t & 127;          // output feature
    const int h = t >> 7;           // k-half
    const int row0 = blockIdx.x * 4;

    ((float*)xs)[t]       = gin[row0 * GIN + t];
    ((float*)xs)[t + 256] = gin[row0 * GIN + t + 256];
    __syncthreads();

    {   // layer 0
        float acc0 = 0.f, acc1 = 0.f, acc2 = 0.f, acc3 = 0.f;
        const float* Wc = W0 + c;
        #pragma unroll 8
        for (int i = h * 64; i < h * 64 + 64; ++i) {
            float w = Wc[i * GH];
            acc0 += xs[0][i] * w; acc1 += xs[1][i] * w;
            acc2 += xs[2][i] * w; acc3 += xs[3][i] * w;
        }
        ps[h][0][c] = acc0; ps[h][1][c] = acc1; ps[h][2][c] = acc2; ps[h][3][c] = acc3;
    }
    __syncthreads();
    {
        int o = t, r = o >> 7, cc = o & 127;
        hs[r][cc] = elu1(ps[0][r][cc] + ps[1][r][cc] + b0[cc]);
        o = t + 256; r = o >> 7; cc = o & 127;
        hs[r][cc] = elu1(ps[0][r][cc] + ps[1][r][cc] + b0[cc]);
    }
    __syncthreads();

    {   // layer 1
        float acc0 = 0.f, acc1 = 0.f, acc2 = 0.f, acc3 = 0.f;
        const float* Wc = W1 + c;
        #pragma unroll 8
        for (int i = h * 64; i < h * 64 + 64; ++i) {
            float w = Wc[i * GH];
            acc0 += hs[0][i] * w; acc1 += hs[1][i] * w;
            acc2 += hs[2][i] * w; acc3 += hs[3][i] * w;
        }
        ps[h][0][c] = acc0; ps[h][1][c] = acc1; ps[h][2][c] = acc2; ps[h][3][c] = acc3;
    }
    __syncthreads();
    {
        int o = t, r = o >> 7, cc = o & 127;
        xs[r][cc] = elu1(ps[0][r][cc] + ps[1][r][cc] + b1[cc]);
        o = t + 256; r = o >> 7; cc = o & 127;
        xs[r][cc] = elu1(ps[0][r][cc] + ps[1][r][cc] + b1[cc]);
    }
    __syncthreads();

    {   // output layer, 8-way k-split
        const int e = t & 7, r = (t >> 3) & 3, q = t >> 5;
        float s = 0.f;
        #pragma unroll
        for (int i = q * 16; i < q * 16 + 16; ++i) s += xs[r][i] * Wo[i * NE + e];
        lp[q][r][e] = s;
    }
    __syncthreads();
    if (t < 32) {
        const int r = t >> 3, e = t & 7;
        float s = bo[e];
        #pragma unroll
        for (int q = 0; q < 8; ++q) s += lp[q][r][e];
        ls[r][e] = s;
    }
    __syncthreads();
    if (t < 4) {
        float mx = ls[t][0];
        #pragma unroll
        for (int e = 1; e < 8; ++e) mx = fmaxf(mx, ls[t][e]);
        float s = 0.f, ex[8];
        #pragma unroll
        for (int e = 0; e < 8; ++e) { ex[e] = expf(ls[t][e] - mx); s += ex[e]; }
        float inv = 1.f / s;
        #pragma unroll
        for (int e = 0; e < 8; ++e) g[(row0 + t) * NE + e] = ex[e] * inv;
    }
}

// ---------------------------------------------------------------------------
// Convert alpha pools AND expert input fp32 -> bf16 in one kernel.
// Destination is contiguous: [ab (3*2^21)] [Xb0 (2^20)]. 4 elems/thread.
// ---------------------------------------------------------------------------
__global__ __launch_bounds__(256) void convert_kernel(
    const float* __restrict__ a0, const float* __restrict__ a1, const float* __restrict__ a2,
    const float* __restrict__ xv, unsigned short* __restrict__ dst)
{
    const long long vi = (long long)(blockIdx.x * blockDim.x + threadIdx.x) * 4;
    const int sel = (int)(vi >> 21);             // 0,1,2 = alpha pools; 3 = X (2^20 elems)
    const float* src = (sel == 0) ? a0 : (sel == 1) ? a1 : (sel == 2) ? a2 : xv;
    float4 v = *(const float4*)(src + (vi & ((1 << 21) - 1)));
    union { unsigned short us[4]; uint2 u2; } p;
    p.us[0] = f2bf(v.x); p.us[1] = f2bf(v.y); p.us[2] = f2bf(v.z); p.us[3] = f2bf(v.w);
    *(uint2*)(dst + vi) = p.u2;
}

// ---------------------------------------------------------------------------
// Fully-fused MoE layer v2.
//  - Block tile 64(M) x 32(N), all 8 experts, BK=32, 16 K-steps.
//  - Double-buffered LDS with T3-minimal prefetch: STAGE(next) issued BEFORE
//    compute(current); single __syncthreads (vmcnt drain) per K-step.
//  - T2 LDS swizzle for 64B rows: byte ^= ((row>>1)&3)<<4, applied via
//    pre-swizzled global source (linear global_load_lds dest) + swizzled
//    ds_read address (both-sides rule).
//  - Expert-split waves: wave w computes experts {2w, 2w+1} over the FULL
//    64x32 tile (af reused 4x, bf reused 4x -> 8 LDS reads per 16 MFMA).
//    Cross-wave sum done once in epilogue via red[] aliased over dead Bs.
// Grid (512/32=16, 2048/64=32) = 512 blocks; LDS 43 KB -> 3 blocks/CU cap.
// ---------------------------------------------------------------------------
__global__ __launch_bounds__(256) void moe_fused_kernel(
    const unsigned short* __restrict__ A,
    const unsigned short* __restrict__ Bw,
    const float* __restrict__ g,
    const float* __restrict__ beta,
    unsigned short* __restrict__ Xnext,
    float* __restrict__ out, int last)
{
    constexpr int K = XIN;
    __shared__ unsigned short As[2][64 * 32];     // 2 x 4 KB
    __shared__ unsigned short Bs[2][8 * 32 * 32]; // 2 x 16 KB
    __shared__ float gs[64][8];                   // 2 KB
    __shared__ float bt[8][32];                   // 1 KB

    const int t = threadIdx.x;
    const int n0 = blockIdx.x * 32;
    const int m0 = blockIdx.y * 64;
    const int wave = t >> 6, lane = t & 63;
    const int e0 = 2 * wave;                      // this wave's expert pair

    // stage g rows (64 x 8) and beta tile (8 x 32); prologue barrier covers.
    ((float2*)gs)[t] = ((const float2*)(g + (size_t)m0 * NE))[t];
    bt[t >> 5][t & 31] = beta[(t >> 5) * UU + n0 + (t & 31)];

    f32x4 acc[2][4][2] = {};   // [expert-in-pair][m-frag][n-frag]

    // ---- staging source addresses (pre-swizzled so linear LDS dest + XOR
    //      read reconstructs row-major logical tile) ----
    const int slot = t & 3;                 // 16B slot within 64B LDS row
    const int arow = t >> 2;                // LDS row this thread fills (A)
    const int acol = ((slot ^ ((arow >> 1) & 3)) * 8);
    const unsigned short* a_src = A + (size_t)(m0 + arow) * K + acol;

    const unsigned short* b_src[4];
    #pragma unroll
    for (int it = 0; it < 4; ++it) {
        const int rowflat = it * 64 + arow;       // 0..255: e = >>5, n = &31
        const int bcol = ((slot ^ ((rowflat >> 1) & 3)) * 8);
        b_src[it] = Bw + ((size_t)(rowflat >> 5) * UU + n0 + (rowflat & 31)) * K + bcol;
    }

#define STAGE(bi, ki)                                                        \
    do {                                                                     \
        __builtin_amdgcn_global_load_lds(                                    \
            (const AS1 void*)(a_src + (ki)),                                 \
            (AS3 void*)(&As[bi][t * 8]), 16, 0, 0);                          \
        _Pragma("unroll")                                                    \
        for (int it_ = 0; it_ < 4; ++it_)                                    \
            __builtin_amdgcn_global_load_lds(                                \
                (const AS1 void*)(b_src[it_] + (ki)),                        \
                (AS3 void*)(&Bs[bi][it_ * 2048 + t * 8]), 16, 0, 0);         \
    } while (0)

#define COMPUTE(bi)                                                          \
    do {                                                                     \
        const int fr_ = lane & 15;                                           \
        const int fkb_ = (lane >> 4) * 16;                                   \
        short8 af_[4], bf_[2][2];                                            \
        _Pragma("unroll")                                                    \
        for (int i = 0; i < 4; ++i) {                                        \
            const int row_ = fr_ + i * 16;                                   \
            af_[i] = *(const short8*)((const char*)(&As[bi][0]) +            \
                     ((row_ * 64 + fkb_) ^ (((row_ >> 1) & 3) << 4)));       \
        }                                                                    \
        _Pragma("unroll")                                                    \
        for (int ep = 0; ep < 2; ++ep)                                       \
            _Pragma("unroll")                                                \
            for (int j = 0; j < 2; ++j) {                                    \
                const int row_ = (e0 + ep) * 32 + j * 16 + fr_;              \
                bf_[ep][j] = *(const short8*)((const char*)(&Bs[bi][0]) +    \
                     ((row_ * 64 + fkb_) ^ (((row_ >> 1) & 3) << 4)));       \
            }                                                                \
        _Pragma("unroll")                                                    \
        for (int ep = 0; ep < 2; ++ep)                                       \
            _Pragma("unroll")                                                \
            for (int i = 0; i < 4; ++i)                                      \
                _Pragma("unroll")                                            \
                for (int j = 0; j < 2; ++j)                                  \
                    acc[ep][i][j] = __builtin_amdgcn_mfma_f32_16x16x32_bf16( \
                        af_[i], bf_[ep][j], acc[ep][i][j], 0, 0, 0);         \
    } while (0)

    // prologue: stage K-step 0 into buf 0
    STAGE(0, 0);
    __syncthreads();

    // main loop: stage(next) -> compute(cur) -> drain+barrier
    for (int step = 0; step < 15; ++step) {
        const int cur = step & 1;
        STAGE(cur ^ 1, (step + 1) * 32);
        COMPUTE(cur);
        __syncthreads();
    }
    COMPUTE(1);   // step 15 (15&1 == 1), no prefetch

    // ---- epilogue: per-wave g/beta blend, cross-wave sum via LDS ----
    __syncthreads();                       // all Bs reads done -> safe to alias
    float* red = (float*)&Bs[0][0];        // 4 waves x 2048 f32 = 32 KB

    const int cl = lane & 15, rq = lane >> 4;
    #pragma unroll
    for (int i = 0; i < 4; ++i)
        #pragma unroll
        for (int j = 0; j < 2; ++j)
            #pragma unroll
            for (int r = 0; r < 4; ++r) {
                const int rl = i * 16 + rq * 4 + r;     // row in tile
                const int co = j * 16 + cl;             // col in tile
                const float v =
                    gs[rl][e0]     * (acc[0][i][j][r] + bt[e0][co]) +
                    gs[rl][e0 + 1] * (acc[1][i][j][r] + bt[e0 + 1][co]);
                red[wave * 2048 + rl * 32 + co] = v;
            }
    __syncthreads();

    // final: thread t -> 8 consecutive outputs (row rl = t>>2, cols c0..c0+7)
    {
        const int rl = t >> 2;
        const int c0 = (t & 3) * 8;
        float v[8];
        #pragma unroll
        for (int u = 0; u < 8; ++u) {
            const int idx = rl * 32 + c0 + u;
            v[u] = red[idx] + red[2048 + idx] + red[4096 + idx] + red[6144 + idx];
        }
        if (last) {
            float4 o0 = {v[0], v[1], v[2], v[3]};
            float4 o1 = {v[4], v[5], v[6], v[7]};
            float* op = out + (size_t)(m0 + rl) * UU + n0 + c0;
            *(float4*)op = o0;
            *(float4*)(op + 4) = o1;
        } else {
            union { unsigned short us[8]; short8 s8; } p;
            #pragma unroll
            for (int u = 0; u < 8; ++u) p.us[u] = f2bf(elu1(v[u]));
            *(short8*)(Xnext + (size_t)(m0 + rl) * UU + n0 + c0) = p.s8;
        }
    }
#undef STAGE
#undef COMPUTE
}

// ---------------------------------------------------------------------------
extern "C" void kernel_launch(void* const* d_in, const int* in_sizes, int n_in,
                              void* d_out, int out_size, void* d_ws, size_t ws_size,
                              hipStream_t stream)
{
    (void)in_sizes; (void)n_in; (void)out_size; (void)ws_size;
    const float* gin = (const float*)d_in[0];
    const float* xin = (const float*)d_in[1];
    const float* W0  = (const float*)d_in[2];
    const float* b0  = (const float*)d_in[3];
    const float* W1  = (const float*)d_in[4];
    const float* b1  = (const float*)d_in[5];
    const float* Wo  = (const float*)d_in[6];
    const float* bo  = (const float*)d_in[7];
    const float* alpha[3] = {(const float*)d_in[8],  (const float*)d_in[10], (const float*)d_in[12]};
    const float* beta[3]  = {(const float*)d_in[9],  (const float*)d_in[11], (const float*)d_in[13]};
    float* out = (float*)d_out;

    // ws layout (~16.8 MB total)
    char* ws = (char*)d_ws;
    float* g = (float*)ws;                                   // 2048*8*4      = 64 KB
    size_t off = 65536;
    unsigned short* ab = (unsigned short*)(ws + off);        // 3 * 2^21 * 2  = 12.58 MB
    off += (size_t)3 * (1 << 21) * 2;
    unsigned short* Xb0 = (unsigned short*)(ws + off);       // 2048*512*2    = 2.1 MB (contiguous after ab!)
    off += (size_t)BATCH * XIN * 2;
    unsigned short* Xb1 = (unsigned short*)(ws + off);       // 2048*512*2    = 2.1 MB
    off += (size_t)BATCH * XIN * 2;

    gating_kernel<<<BATCH / 4, 256, 0, stream>>>(gin, W0, b0, W1, b1, Wo, bo, g);
    // converts 3 alpha pools + X in one pass; X lands at ab + 3*2^21 == Xb0
    convert_kernel<<<(3 * (1 << 21) + BATCH * XIN) / 4 / 256, 256, 0, stream>>>(
        alpha[0], alpha[1], alpha[2], xin, ab);

    // ping-pong X buffers: layer reads Xsrc while writing Xdst.
    unsigned short* Xsrc = Xb0;
    unsigned short* Xdst = Xb1;
    for (int l = 0; l < 3; ++l) {
        moe_fused_kernel<<<dim3(UU / 32, BATCH / 64), 256, 0, stream>>>(
            Xsrc, ab + (size_t)l * (1 << 21), g, beta[l], Xdst, out, l == 2 ? 1 : 0);
        unsigned short* tmp = Xsrc; Xsrc = Xdst; Xdst = tmp;
    }
}